// Round 8
// baseline (295.006 us; speedup 1.0000x reference)
//
#include <hip/hip_runtime.h>
#include <hip/hip_bf16.h>
#include <math.h>

#define N 256
#define D 768
#define BATCH 128

typedef float f32x4 __attribute__((ext_vector_type(4)));
typedef short bf16x8 __attribute__((ext_vector_type(8)));

// RNE fp32 -> bf16 (no NaN inputs in this problem)
static __device__ __forceinline__ unsigned short f2bf(float f) {
    unsigned int u = __float_as_uint(f);
    u += 0x7fffu + ((u >> 16) & 1u);
    return (unsigned short)(u >> 16);
}
static __device__ __forceinline__ unsigned int pack2bf(float lo, float hi) {
    unsigned int a = __float_as_uint(lo);
    unsigned int b = __float_as_uint(hi);
    a += 0x7fffu + ((a >> 16) & 1u);
    b += 0x7fffu + ((b >> 16) & 1u);
    return (a >> 16) | (b & 0xffff0000u);
}

// ---- Stage 1 (fused): a2 (96 blk) + topk (64 blk) + gram-selfnorm (128 blk)
// gram normalizes OUTPUT (dot(raw_i,raw_j)*invn_i*invn_j == dot of normalized
// rows) so it depends only on kernel inputs -> co-launches with a2/topk.
// k_norm deleted entirely.
__global__ void k_stage1(const float* __restrict__ cf, const float* __restrict__ ctx,
                         const float* __restrict__ w1, float* __restrict__ a,
                         const int* __restrict__ co, float* __restrict__ topv,
                         int* __restrict__ topi,
                         float* __restrict__ vs, float* __restrict__ cs) {
    __shared__ float sm[2 * 64 * 33];        // a2 Ci+Wj / gram Li+Lj
    __shared__ float nsum[64][5];
    __shared__ float invn[64];
    int bx = blockIdx.x;
    int t = threadIdx.x;                     // 256
    if (bx < 96) {
        // ---- a = cf @ w1, 32x32 tiles ----
        int bi = bx;
        int i0 = (bi / 12) * 32, j0 = (bi % 12) * 32;
        float (*Ci)[33] = (float(*)[33])sm;
        float (*Wj)[33] = (float(*)[33])(sm + 64 * 33);
        int tx = t & 15, ty = t >> 4;
        float a00 = 0.f, a01 = 0.f, a10 = 0.f, a11 = 0.f;
        for (int k0 = 0; k0 < 768; k0 += 64) {
            #pragma unroll
            for (int s = 0; s < 8; s++) {
                int idx = s * 256 + t;
                int row = idx >> 6, kc = idx & 63;
                Ci[kc][row] = cf[(i0 + row) * 768 + k0 + kc];
                int kr = idx >> 5, col = idx & 31;
                Wj[kr][col] = w1[(k0 + kr) * 384 + j0 + col];
            }
            __syncthreads();
            #pragma unroll 4
            for (int kk = 0; kk < 64; kk++) {
                float iv0 = Ci[kk][ty * 2], iv1 = Ci[kk][ty * 2 + 1];
                float jv0 = Wj[kk][tx * 2], jv1 = Wj[kk][tx * 2 + 1];
                a00 += iv0 * jv0; a01 += iv0 * jv1;
                a10 += iv1 * jv0; a11 += iv1 * jv1;
            }
            __syncthreads();
        }
        a[(i0 + ty * 2)     * 384 + j0 + tx * 2]     = a00;
        a[(i0 + ty * 2)     * 384 + j0 + tx * 2 + 1] = a01;
        a[(i0 + ty * 2 + 1) * 384 + j0 + tx * 2]     = a10;
        a[(i0 + ty * 2 + 1) * 384 + j0 + tx * 2 + 1] = a11;
    } else if (bx < 160) {
        // ---- top-5, one wave per row; named regs (rule #20: no indexed arr)
        int lane = t & 63;
        int row = (bx - 96) * 4 + (t >> 6);
        int4 v4 = *(const int4*)(co + row * 256 + lane * 4);
        int k0 = v4.x * 256 + (255 - (lane * 4 + 0));
        int k1 = v4.y * 256 + (255 - (lane * 4 + 1));
        int k2 = v4.z * 256 + (255 - (lane * 4 + 2));
        int k3 = v4.w * 256 + (255 - (lane * 4 + 3));
        for (int r = 0; r < 5; r++) {
            int best = max(max(k0, k1), max(k2, k3));
            #pragma unroll
            for (int off = 32; off > 0; off >>= 1) best = max(best, __shfl_xor(best, off, 64));
            int kidx = 255 - (best & 255);
            int val = best >> 8;
            if (lane == 0) { topv[row * 5 + r] = (float)val; topi[row * 5 + r] = kidx; }
            if ((kidx >> 2) == lane) {
                int sel = kidx & 3;
                k0 = (sel == 0) ? -1 : k0;
                k1 = (sel == 1) ? -1 : k1;
                k2 = (sel == 2) ? -1 : k2;
                k3 = (sel == 3) ? -1 : k3;
            }
        }
    } else {
        // ---- gram (vs/cs), 32x32 tiles, self-normalizing ----
        int bx2 = bx - 160;                  // 0..127
        const float* S = (bx2 >= 64) ? ctx : cf;
        float* O       = (bx2 >= 64) ? cs  : vs;
        int bi = bx2 & 63;
        int i0 = (bi >> 3) * 32, j0 = (bi & 7) * 32;
        // phase 0: inv-norms of the 32 i-rows and 32 j-rows
        {
            int r = t >> 2, p = t & 3;
            const float* Srow = S + (size_t)((r < 32) ? (i0 + r) : (j0 + r - 32)) * 768;
            float sq = 0.f;
            for (int j = 0; j < 192; j++) { float v = Srow[p + 4 * j]; sq += v * v; }
            nsum[r][p] = sq;
        }
        __syncthreads();
        if (t < 64) invn[t] = 1.0f / sqrtf(nsum[t][0] + nsum[t][1] + nsum[t][2] + nsum[t][3]);
        __syncthreads();
        float (*Li)[33] = (float(*)[33])sm;
        float (*Lj)[33] = (float(*)[33])(sm + 64 * 33);
        int tx = t & 15, ty = t >> 4;
        float a00 = 0.f, a01 = 0.f, a10 = 0.f, a11 = 0.f;
        for (int k0 = 0; k0 < 768; k0 += 64) {
            #pragma unroll
            for (int s = 0; s < 8; s++) {
                int idx = s * 256 + t;
                int row = idx >> 6, kc = idx & 63;
                Li[kc][row] = S[(i0 + row) * 768 + k0 + kc];
                Lj[kc][row] = S[(j0 + row) * 768 + k0 + kc];
            }
            __syncthreads();
            #pragma unroll 4
            for (int kk = 0; kk < 64; kk++) {
                float iv0 = Li[kk][ty * 2], iv1 = Li[kk][ty * 2 + 1];
                float jv0 = Lj[kk][tx * 2], jv1 = Lj[kk][tx * 2 + 1];
                a00 += iv0 * jv0; a01 += iv0 * jv1;
                a10 += iv1 * jv0; a11 += iv1 * jv1;
            }
            __syncthreads();
        }
        float ni0 = invn[ty * 2], ni1 = invn[ty * 2 + 1];
        float nj0 = invn[32 + tx * 2], nj1 = invn[32 + tx * 2 + 1];
        O[(i0 + ty * 2)     * 256 + j0 + tx * 2]     = a00 * ni0 * nj0;
        O[(i0 + ty * 2)     * 256 + j0 + tx * 2 + 1] = a01 * ni0 * nj1;
        O[(i0 + ty * 2 + 1) * 256 + j0 + tx * 2]     = a10 * ni1 * nj0;
        O[(i0 + ty * 2 + 1) * 256 + j0 + tx * 2 + 1] = a11 * ni1 * nj1;
    }
}

// ---------------- Stage 3 (fused): e1t (256 blk) + shared2 (64 blk) --------
__global__ void k_stage3(const float* __restrict__ a, const float* __restrict__ b1,
                         const float* __restrict__ w2, const float* __restrict__ b2,
                         const float* __restrict__ vs, const float* __restrict__ cs,
                         const int* __restrict__ ic, float* __restrict__ e1,
                         const int* __restrict__ co, float* __restrict__ ss,
                         float* __restrict__ sc) {
    __shared__ float sm[12800];          // 51200 B: e1t ai/ajm/sw2 OR shared2 tiles
    int bx = blockIdx.x;
    int t = threadIdx.x;
    if (bx < 256) {
        // ---- e1 pair-tiled 16x16 ----
        int i0 = (bx >> 4) * 16, j0 = (bx & 15) * 16;
        float (*ai)[388]  = (float(*)[388])sm;
        float (*ajm)[388] = (float(*)[388])(sm + 16 * 388);
        float* sw2 = sm + 2 * 16 * 388;
        for (int idx = t; idx < 16 * 96; idx += 256) {
            int r = idx / 96, c = (idx % 96) * 4;
            *(float4*)&ai[r][c] = *(const float4*)(a + (i0 + r) * 384 + c);
            float4 u  = *(const float4*)(a + (j0 + r) * 384 + c);
            float4 bb = *(const float4*)(b1 + c);
            u.x -= bb.x; u.y -= bb.y; u.z -= bb.z; u.w -= bb.w;
            *(float4*)&ajm[r][c] = u;
        }
        for (int k = t; k < 384; k += 256) sw2[k] = w2[k];
        __syncthreads();
        int tx = t & 15, ty = t >> 4;
        float s = 0.f;
        #pragma unroll 4
        for (int k4 = 0; k4 < 96; k4++) {
            float4 xv = *(const float4*)&ai[ty][k4 * 4];
            float4 yv = *(const float4*)&ajm[tx][k4 * 4];
            float4 wv = *(const float4*)&sw2[k4 * 4];
            s += fmaxf(xv.x - yv.x, 0.f) * wv.x;
            s += fmaxf(xv.y - yv.y, 0.f) * wv.y;
            s += fmaxf(xv.z - yv.z, 0.f) * wv.z;
            s += fmaxf(xv.w - yv.w, 0.f) * wv.w;
        }
        int i = i0 + ty, j = j0 + tx;
        float sig = 1.0f / (1.0f + expf(-(s + b2[0])));
        float comb = 0.7f * vs[i * 256 + j] + 0.3f * cs[i * 256 + j];
        float ci = (float)ic[i], cj = (float)ic[j];
        float mn = fminf(ci, cj), mx = fmaxf(ci, cj);
        float ratio = mn / fmaxf(mx, 1.0f);
        e1[i * 256 + j] = comb * sig * ratio;
    } else {
        // ---- shared_sum/cnt 32x32 tiles ----
        int bi = bx - 256;
        int i0 = (bi >> 3) * 32, j0 = (bi & 7) * 32;
        float (*Mi)[33] = (float(*)[33])sm;
        float (*Ai)[33] = (float(*)[33])(sm + 2112);
        float (*Mj)[33] = (float(*)[33])(sm + 4224);
        float (*Aj)[33] = (float(*)[33])(sm + 6336);
        int tx = t & 15, ty = t >> 4;
        float s00=0.f,s01=0.f,s10=0.f,s11=0.f;
        float c00=0.f,c01=0.f,c10=0.f,c11=0.f;
        for (int k0 = 0; k0 < 256; k0 += 64) {
            #pragma unroll
            for (int s = 0; s < 8; s++) {
                int idx = s * 256 + t;
                int row = idx >> 6, kc = idx & 63;
                int civ = co[(i0 + row) * 256 + k0 + kc];
                float aa = civ > 50 ? 1.f : 0.f;
                Ai[kc][row] = aa;
                Mi[kc][row] = aa * vs[(i0 + row) * 256 + k0 + kc];
                int cjv = co[(j0 + row) * 256 + k0 + kc];
                float ab = cjv > 50 ? 1.f : 0.f;
                Aj[kc][row] = ab;
                Mj[kc][row] = ab * vs[(j0 + row) * 256 + k0 + kc];
            }
            __syncthreads();
            #pragma unroll 4
            for (int kk = 0; kk < 64; kk++) {
                float mi0 = Mi[kk][ty*2], mi1 = Mi[kk][ty*2+1];
                float ai0 = Ai[kk][ty*2], ai1 = Ai[kk][ty*2+1];
                float mj0 = Mj[kk][tx*2], mj1 = Mj[kk][tx*2+1];
                float aj0 = Aj[kk][tx*2], aj1 = Aj[kk][tx*2+1];
                s00 += mi0*mj0; s01 += mi0*mj1; s10 += mi1*mj0; s11 += mi1*mj1;
                c00 += ai0*aj0; c01 += ai0*aj1; c10 += ai1*aj0; c11 += ai1*aj1;
            }
            __syncthreads();
        }
        ss[(i0+ty*2)  *256 + j0+tx*2]   = s00; ss[(i0+ty*2)  *256 + j0+tx*2+1] = s01;
        ss[(i0+ty*2+1)*256 + j0+tx*2]   = s10; ss[(i0+ty*2+1)*256 + j0+tx*2+1] = s11;
        sc[(i0+ty*2)  *256 + j0+tx*2]   = c00; sc[(i0+ty*2)  *256 + j0+tx*2+1] = c01;
        sc[(i0+ty*2+1)*256 + j0+tx*2]   = c10; sc[(i0+ty*2+1)*256 + j0+tx*2+1] = c11;
    }
}

// ---------------- K7: assemble E (tiered), zero diag, per-row max -----------
__global__ void k_assemble(const int* __restrict__ co, const float* __restrict__ vs,
                           const float* __restrict__ cs, const float* __restrict__ e1,
                           const float* __restrict__ ss, const float* __restrict__ sc,
                           const float* __restrict__ topv, const int* __restrict__ topi,
                           float* __restrict__ E, float* __restrict__ partials) {
    int i = blockIdx.x, j = threadIdx.x;
    int cij = co[i * 256 + j];
    float e;
    if (i == j) {
        e = 0.f;
    } else if (cij > 50) {
        e = e1[i * 256 + j];
    } else if (cij > 10) {
        float conf = (float)cij / 50.0f;
        float comb = 0.7f * vs[i * 256 + j] + 0.3f * cs[i * 256 + j];
        float cnt = sc[i * 256 + j];
        float avg = ss[i * 256 + j] / fmaxf(cnt, 1.f);
        e = (cnt > 0.f) ? conf * comb + (1.f - conf) * avg : conf * comb;
    } else {
        float tvi[5], tvj[5]; int tii[5], tij[5];
        #pragma unroll
        for (int k = 0; k < 5; k++) {
            tvi[k] = topv[i * 5 + k]; tii[k] = topi[i * 5 + k];
            tvj[k] = topv[j * 5 + k]; tij[k] = topi[j * 5 + k];
        }
        float trans = 0.f, tot = 0.f;
        #pragma unroll
        for (int k = 0; k < 5; k++) {
            if (!(tvi[k] > 10.f)) continue;
            float vin_i = vs[i * 256 + tii[k]];
            #pragma unroll
            for (int l = 0; l < 5; l++) {
                if (!(tvj[l] > 10.f)) continue;
                int cc = co[tii[k] * 256 + tij[l]];
                if (cc <= 0) continue;
                float w = tvi[k] * tvj[l] / 50.f;
                float sim = vin_i * vs[j * 256 + tij[l]] * vs[tii[k] * 256 + tij[l]];
                trans += w * sim; tot += w;
            }
        }
        e = (tot > 0.f) ? trans / tot : 0.1f * cs[i * 256 + j];
    }
    E[i * 256 + j] = e;
    __shared__ float red[256];
    red[j] = e; __syncthreads();
    for (int off = 128; off > 0; off >>= 1) {
        if (j < off) red[j] = fmaxf(red[j], red[j + off]);
        __syncthreads();
    }
    if (j == 0) partials[i] = red[0];
}

// ---------------- K9: out = (I + E/mx) @ x, k_ep FOLDED IN ------------------
// Core = r6-verified barrier-free structure (plain C++ only). New vs r6:
//  * s = 1/max: per-wave shuffle-max over partials[256] (no barrier, all
//    waves compute identically).
//  * B-frags built from E fp32 (L2-hot): fe = s*E + (row==col), pack2bf --
//    bit-identical numeric path to the deleted k_ep.
__global__ __launch_bounds__(256) void k_einsum_bf(
    const float* __restrict__ E, const float* __restrict__ partials,
    const float* __restrict__ x, float* __restrict__ out) {
    __shared__ __align__(16) unsigned short xt[64 * 264];   // 33792 B
    int t = threadIdx.x;
    int b = blockIdx.y;
    int d0 = blockIdx.x * 64;
    int lane = t & 63, w = t >> 6;
    int l15 = lane & 15, lq = lane >> 4;

    // ---- s = 1/max(E) via per-wave shuffle reduce ----
    float pm = fmaxf(fmaxf(partials[lane * 4], partials[lane * 4 + 1]),
                     fmaxf(partials[lane * 4 + 2], partials[lane * 4 + 3]));
    #pragma unroll
    for (int off = 32; off > 0; off >>= 1) pm = fmaxf(pm, __shfl_xor(pm, off, 64));
    float s = (pm > 0.f) ? 1.0f / pm : 1.0f;

    // ---- staging (identical to r6): thread (d = t&63, k-octet ko = t>>6) ----
    int dl = t & 63;
    int ko = t >> 6;
    const float* xb = x + ((size_t)b * 256 + ko * 8) * 768 + d0 + dl;

    float v[8][8];
    #pragma unroll
    for (int kt = 0; kt < 8; kt++)
        #pragma unroll
        for (int sidx = 0; sidx < 8; sidx++)
            v[kt][sidx] = xb[((size_t)kt * 32 + sidx) * 768];
    #pragma unroll
    for (int kt = 0; kt < 8; kt++) {
        uint4 pv;
        pv.x = pack2bf(v[kt][0], v[kt][1]);
        pv.y = pack2bf(v[kt][2], v[kt][3]);
        pv.z = pack2bf(v[kt][4], v[kt][5]);
        pv.w = pack2bf(v[kt][6], v[kt][7]);
        *(uint4*)&xt[dl * 264 + kt * 32 + ko * 8] = pv;
    }
    __syncthreads();   // the ONE barrier

    f32x4 acc[4][4];
    #pragma unroll
    for (int mf = 0; mf < 4; mf++)
        #pragma unroll
        for (int nf = 0; nf < 4; nf++)
            #pragma unroll
            for (int e = 0; e < 4; e++) acc[mf][nf][e] = 0.f;

    // E row base for this lane: row (w*64 + nf*16 + l15), col (kt*32 + lq*8)
    const float* erow = E + (((w * 64 + l15) << 8) + lq * 8);
    int wi = w * 64 + l15;

    // ---- barrier-free k-loop, all plain ops ----
    #pragma unroll
    for (int kt = 0; kt < 8; kt++) {
        uint4 bvb[4];
        #pragma unroll
        for (int nf = 0; nf < 4; nf++) {
            float4 fa = *(const float4*)(erow + (nf << 12) + kt * 32);
            float4 fb = *(const float4*)(erow + (nf << 12) + kt * 32 + 4);
            int i = wi + nf * 16;
            int kb = kt * 32 + lq * 8;
            float e0 = s * fa.x + ((kb + 0 == i) ? 1.f : 0.f);
            float e1 = s * fa.y + ((kb + 1 == i) ? 1.f : 0.f);
            float e2 = s * fa.z + ((kb + 2 == i) ? 1.f : 0.f);
            float e3 = s * fa.w + ((kb + 3 == i) ? 1.f : 0.f);
            float e4 = s * fb.x + ((kb + 4 == i) ? 1.f : 0.f);
            float e5 = s * fb.y + ((kb + 5 == i) ? 1.f : 0.f);
            float e6 = s * fb.z + ((kb + 6 == i) ? 1.f : 0.f);
            float e7 = s * fb.w + ((kb + 7 == i) ? 1.f : 0.f);
            uint4 pv;
            pv.x = pack2bf(e0, e1); pv.y = pack2bf(e2, e3);
            pv.z = pack2bf(e4, e5); pv.w = pack2bf(e6, e7);
            bvb[nf] = pv;
        }
        bf16x8 af[4];
        #pragma unroll
        for (int g = 0; g < 4; g++)
            af[g] = *(const bf16x8*)&xt[(g * 16 + l15) * 264 + kt * 32 + lq * 8];
        #pragma unroll
        for (int mf = 0; mf < 4; mf++)
            #pragma unroll
            for (int nf = 0; nf < 4; nf++)
                acc[mf][nf] = __builtin_amdgcn_mfma_f32_16x16x32_bf16(
                    af[mf], *(const bf16x8*)&bvb[nf], acc[mf][nf], 0, 0, 0);
    }

    // epilogue: D rows = d (lq*4+reg -> 4 consecutive d), cols = i (l15)
    float* ob = out + ((size_t)b * 256) * 768 + d0;
    #pragma unroll
    for (int mf = 0; mf < 4; mf++) {
        #pragma unroll
        for (int nf = 0; nf < 4; nf++) {
            int i = w * 64 + nf * 16 + l15;
            int d = mf * 16 + lq * 4;
            *(float4*)(ob + (size_t)i * 768 + d) = *(float4*)&acc[mf][nf];
        }
    }
}

extern "C" void kernel_launch(void* const* d_in, const int* in_sizes, int n_in,
                              void* d_out, int out_size, void* d_ws, size_t ws_size,
                              hipStream_t stream) {
    const float* x   = (const float*)d_in[0];
    const float* cf  = (const float*)d_in[1];
    const float* ctx = (const float*)d_in[2];
    const float* w1  = (const float*)d_in[3];
    const float* b1  = (const float*)d_in[4];
    const float* w2  = (const float*)d_in[5];
    const float* b2  = (const float*)d_in[6];
    const int*   co  = (const int*)d_in[7];
    const int*   ic  = (const int*)d_in[8];
    float* out = (float*)d_out;

    float* ws   = (float*)d_ws;
    float* vsn  = ws;                        // 196608 (unused, layout kept)
    float* csn  = vsn + 196608;              // 196608 (unused)
    float* a    = csn + 196608;              // 98304
    float* vs   = a + 98304;                 // 65536
    float* cs   = vs + 65536;                // 65536
    float* e1   = cs + 65536;                // 65536
    float* ss   = e1 + 65536;                // 65536
    float* sc   = ss + 65536;                // 65536
    float* E    = sc + 65536;                // 65536
    float* topv = E + 65536;                 // 1280
    int*   topi = (int*)(topv + 1280);       // 1280
    float* partials = (float*)(topi + 1280); // 256

    k_stage1<<<288, 256, 0, stream>>>(cf, ctx, w1, a, co, topv, topi, vs, cs);
    k_stage3<<<320, 256, 0, stream>>>(a, b1, w2, b2, vs, cs, ic, e1, co, ss, sc);
    k_assemble<<<256, 256, 0, stream>>>(co, vs, cs, e1, ss, sc, topv, topi, E, partials);
    k_einsum_bf<<<dim3(12, BATCH), 256, 0, stream>>>(E, partials, x, out);
}

// Round 9
// 258.810 us; speedup vs baseline: 1.1399x; 1.1399x over previous
//
#include <hip/hip_runtime.h>
#include <hip/hip_bf16.h>
#include <math.h>

#define N 256
#define D 768
#define BATCH 128

typedef float f32x4 __attribute__((ext_vector_type(4)));
typedef short bf16x8 __attribute__((ext_vector_type(8)));

// RNE fp32 -> bf16 (no NaN inputs in this problem)
static __device__ __forceinline__ unsigned short f2bf(float f) {
    unsigned int u = __float_as_uint(f);
    u += 0x7fffu + ((u >> 16) & 1u);
    return (unsigned short)(u >> 16);
}
static __device__ __forceinline__ unsigned int pack2bf(float lo, float hi) {
    unsigned int a = __float_as_uint(lo);
    unsigned int b = __float_as_uint(hi);
    a += 0x7fffu + ((a >> 16) & 1u);
    b += 0x7fffu + ((b >> 16) & 1u);
    return (a >> 16) | (b & 0xffff0000u);
}

// ---- Stage 1 (fused, r8-VERIFIED): a2 (96) + topk (64) + gram-selfnorm (128)
__global__ void k_stage1(const float* __restrict__ cf, const float* __restrict__ ctx,
                         const float* __restrict__ w1, float* __restrict__ a,
                         const int* __restrict__ co, float* __restrict__ topv,
                         int* __restrict__ topi,
                         float* __restrict__ vs, float* __restrict__ cs) {
    __shared__ float sm[2 * 64 * 33];        // a2 Ci+Wj / gram Li+Lj
    __shared__ float nsum[64][5];
    __shared__ float invn[64];
    int bx = blockIdx.x;
    int t = threadIdx.x;                     // 256
    if (bx < 96) {
        // ---- a = cf @ w1, 32x32 tiles ----
        int bi = bx;
        int i0 = (bi / 12) * 32, j0 = (bi % 12) * 32;
        float (*Ci)[33] = (float(*)[33])sm;
        float (*Wj)[33] = (float(*)[33])(sm + 64 * 33);
        int tx = t & 15, ty = t >> 4;
        float a00 = 0.f, a01 = 0.f, a10 = 0.f, a11 = 0.f;
        for (int k0 = 0; k0 < 768; k0 += 64) {
            #pragma unroll
            for (int s = 0; s < 8; s++) {
                int idx = s * 256 + t;
                int row = idx >> 6, kc = idx & 63;
                Ci[kc][row] = cf[(i0 + row) * 768 + k0 + kc];
                int kr = idx >> 5, col = idx & 31;
                Wj[kr][col] = w1[(k0 + kr) * 384 + j0 + col];
            }
            __syncthreads();
            #pragma unroll 4
            for (int kk = 0; kk < 64; kk++) {
                float iv0 = Ci[kk][ty * 2], iv1 = Ci[kk][ty * 2 + 1];
                float jv0 = Wj[kk][tx * 2], jv1 = Wj[kk][tx * 2 + 1];
                a00 += iv0 * jv0; a01 += iv0 * jv1;
                a10 += iv1 * jv0; a11 += iv1 * jv1;
            }
            __syncthreads();
        }
        a[(i0 + ty * 2)     * 384 + j0 + tx * 2]     = a00;
        a[(i0 + ty * 2)     * 384 + j0 + tx * 2 + 1] = a01;
        a[(i0 + ty * 2 + 1) * 384 + j0 + tx * 2]     = a10;
        a[(i0 + ty * 2 + 1) * 384 + j0 + tx * 2 + 1] = a11;
    } else if (bx < 160) {
        // ---- top-5, one wave per row; named regs (rule #20) ----
        int lane = t & 63;
        int row = (bx - 96) * 4 + (t >> 6);
        int4 v4 = *(const int4*)(co + row * 256 + lane * 4);
        int k0 = v4.x * 256 + (255 - (lane * 4 + 0));
        int k1 = v4.y * 256 + (255 - (lane * 4 + 1));
        int k2 = v4.z * 256 + (255 - (lane * 4 + 2));
        int k3 = v4.w * 256 + (255 - (lane * 4 + 3));
        for (int r = 0; r < 5; r++) {
            int best = max(max(k0, k1), max(k2, k3));
            #pragma unroll
            for (int off = 32; off > 0; off >>= 1) best = max(best, __shfl_xor(best, off, 64));
            int kidx = 255 - (best & 255);
            int val = best >> 8;
            if (lane == 0) { topv[row * 5 + r] = (float)val; topi[row * 5 + r] = kidx; }
            if ((kidx >> 2) == lane) {
                int sel = kidx & 3;
                k0 = (sel == 0) ? -1 : k0;
                k1 = (sel == 1) ? -1 : k1;
                k2 = (sel == 2) ? -1 : k2;
                k3 = (sel == 3) ? -1 : k3;
            }
        }
    } else {
        // ---- gram (vs/cs), 32x32 tiles, self-normalizing ----
        int bx2 = bx - 160;                  // 0..127
        const float* S = (bx2 >= 64) ? ctx : cf;
        float* O       = (bx2 >= 64) ? cs  : vs;
        int bi = bx2 & 63;
        int i0 = (bi >> 3) * 32, j0 = (bi & 7) * 32;
        {
            int r = t >> 2, p = t & 3;
            const float* Srow = S + (size_t)((r < 32) ? (i0 + r) : (j0 + r - 32)) * 768;
            float sq = 0.f;
            for (int j = 0; j < 192; j++) { float v = Srow[p + 4 * j]; sq += v * v; }
            nsum[r][p] = sq;
        }
        __syncthreads();
        if (t < 64) invn[t] = 1.0f / sqrtf(nsum[t][0] + nsum[t][1] + nsum[t][2] + nsum[t][3]);
        __syncthreads();
        float (*Li)[33] = (float(*)[33])sm;
        float (*Lj)[33] = (float(*)[33])(sm + 64 * 33);
        int tx = t & 15, ty = t >> 4;
        float a00 = 0.f, a01 = 0.f, a10 = 0.f, a11 = 0.f;
        for (int k0 = 0; k0 < 768; k0 += 64) {
            #pragma unroll
            for (int s = 0; s < 8; s++) {
                int idx = s * 256 + t;
                int row = idx >> 6, kc = idx & 63;
                Li[kc][row] = S[(i0 + row) * 768 + k0 + kc];
                Lj[kc][row] = S[(j0 + row) * 768 + k0 + kc];
            }
            __syncthreads();
            #pragma unroll 4
            for (int kk = 0; kk < 64; kk++) {
                float iv0 = Li[kk][ty * 2], iv1 = Li[kk][ty * 2 + 1];
                float jv0 = Lj[kk][tx * 2], jv1 = Lj[kk][tx * 2 + 1];
                a00 += iv0 * jv0; a01 += iv0 * jv1;
                a10 += iv1 * jv0; a11 += iv1 * jv1;
            }
            __syncthreads();
        }
        float ni0 = invn[ty * 2], ni1 = invn[ty * 2 + 1];
        float nj0 = invn[32 + tx * 2], nj1 = invn[32 + tx * 2 + 1];
        O[(i0 + ty * 2)     * 256 + j0 + tx * 2]     = a00 * ni0 * nj0;
        O[(i0 + ty * 2)     * 256 + j0 + tx * 2 + 1] = a01 * ni0 * nj1;
        O[(i0 + ty * 2 + 1) * 256 + j0 + tx * 2]     = a10 * ni1 * nj0;
        O[(i0 + ty * 2 + 1) * 256 + j0 + tx * 2 + 1] = a11 * ni1 * nj1;
    }
}

// ---------------- Stage 3 (fused, verified): e1t (256) + shared2 (64) ------
__global__ void k_stage3(const float* __restrict__ a, const float* __restrict__ b1,
                         const float* __restrict__ w2, const float* __restrict__ b2,
                         const float* __restrict__ vs, const float* __restrict__ cs,
                         const int* __restrict__ ic, float* __restrict__ e1,
                         const int* __restrict__ co, float* __restrict__ ss,
                         float* __restrict__ sc) {
    __shared__ float sm[12800];
    int bx = blockIdx.x;
    int t = threadIdx.x;
    if (bx < 256) {
        int i0 = (bx >> 4) * 16, j0 = (bx & 15) * 16;
        float (*ai)[388]  = (float(*)[388])sm;
        float (*ajm)[388] = (float(*)[388])(sm + 16 * 388);
        float* sw2 = sm + 2 * 16 * 388;
        for (int idx = t; idx < 16 * 96; idx += 256) {
            int r = idx / 96, c = (idx % 96) * 4;
            *(float4*)&ai[r][c] = *(const float4*)(a + (i0 + r) * 384 + c);
            float4 u  = *(const float4*)(a + (j0 + r) * 384 + c);
            float4 bb = *(const float4*)(b1 + c);
            u.x -= bb.x; u.y -= bb.y; u.z -= bb.z; u.w -= bb.w;
            *(float4*)&ajm[r][c] = u;
        }
        for (int k = t; k < 384; k += 256) sw2[k] = w2[k];
        __syncthreads();
        int tx = t & 15, ty = t >> 4;
        float s = 0.f;
        #pragma unroll 4
        for (int k4 = 0; k4 < 96; k4++) {
            float4 xv = *(const float4*)&ai[ty][k4 * 4];
            float4 yv = *(const float4*)&ajm[tx][k4 * 4];
            float4 wv = *(const float4*)&sw2[k4 * 4];
            s += fmaxf(xv.x - yv.x, 0.f) * wv.x;
            s += fmaxf(xv.y - yv.y, 0.f) * wv.y;
            s += fmaxf(xv.z - yv.z, 0.f) * wv.z;
            s += fmaxf(xv.w - yv.w, 0.f) * wv.w;
        }
        int i = i0 + ty, j = j0 + tx;
        float sig = 1.0f / (1.0f + expf(-(s + b2[0])));
        float comb = 0.7f * vs[i * 256 + j] + 0.3f * cs[i * 256 + j];
        float ci = (float)ic[i], cj = (float)ic[j];
        float mn = fminf(ci, cj), mx = fmaxf(ci, cj);
        float ratio = mn / fmaxf(mx, 1.0f);
        e1[i * 256 + j] = comb * sig * ratio;
    } else {
        int bi = bx - 256;
        int i0 = (bi >> 3) * 32, j0 = (bi & 7) * 32;
        float (*Mi)[33] = (float(*)[33])sm;
        float (*Ai)[33] = (float(*)[33])(sm + 2112);
        float (*Mj)[33] = (float(*)[33])(sm + 4224);
        float (*Aj)[33] = (float(*)[33])(sm + 6336);
        int tx = t & 15, ty = t >> 4;
        float s00=0.f,s01=0.f,s10=0.f,s11=0.f;
        float c00=0.f,c01=0.f,c10=0.f,c11=0.f;
        for (int k0 = 0; k0 < 256; k0 += 64) {
            #pragma unroll
            for (int s = 0; s < 8; s++) {
                int idx = s * 256 + t;
                int row = idx >> 6, kc = idx & 63;
                int civ = co[(i0 + row) * 256 + k0 + kc];
                float aa = civ > 50 ? 1.f : 0.f;
                Ai[kc][row] = aa;
                Mi[kc][row] = aa * vs[(i0 + row) * 256 + k0 + kc];
                int cjv = co[(j0 + row) * 256 + k0 + kc];
                float ab = cjv > 50 ? 1.f : 0.f;
                Aj[kc][row] = ab;
                Mj[kc][row] = ab * vs[(j0 + row) * 256 + k0 + kc];
            }
            __syncthreads();
            #pragma unroll 4
            for (int kk = 0; kk < 64; kk++) {
                float mi0 = Mi[kk][ty*2], mi1 = Mi[kk][ty*2+1];
                float ai0 = Ai[kk][ty*2], ai1 = Ai[kk][ty*2+1];
                float mj0 = Mj[kk][tx*2], mj1 = Mj[kk][tx*2+1];
                float aj0 = Aj[kk][tx*2], aj1 = Aj[kk][tx*2+1];
                s00 += mi0*mj0; s01 += mi0*mj1; s10 += mi1*mj0; s11 += mi1*mj1;
                c00 += ai0*aj0; c01 += ai0*aj1; c10 += ai1*aj0; c11 += ai1*aj1;
            }
            __syncthreads();
        }
        ss[(i0+ty*2)  *256 + j0+tx*2]   = s00; ss[(i0+ty*2)  *256 + j0+tx*2+1] = s01;
        ss[(i0+ty*2+1)*256 + j0+tx*2]   = s10; ss[(i0+ty*2+1)*256 + j0+tx*2+1] = s11;
        sc[(i0+ty*2)  *256 + j0+tx*2]   = c00; sc[(i0+ty*2)  *256 + j0+tx*2+1] = c01;
        sc[(i0+ty*2+1)*256 + j0+tx*2]   = c10; sc[(i0+ty*2+1)*256 + j0+tx*2+1] = c11;
    }
}

// ---------------- K7: assemble E (tiered), zero diag, per-row max -----------
__global__ void k_assemble(const int* __restrict__ co, const float* __restrict__ vs,
                           const float* __restrict__ cs, const float* __restrict__ e1,
                           const float* __restrict__ ss, const float* __restrict__ sc,
                           const float* __restrict__ topv, const int* __restrict__ topi,
                           float* __restrict__ E, float* __restrict__ partials) {
    int i = blockIdx.x, j = threadIdx.x;
    int cij = co[i * 256 + j];
    float e;
    if (i == j) {
        e = 0.f;
    } else if (cij > 50) {
        e = e1[i * 256 + j];
    } else if (cij > 10) {
        float conf = (float)cij / 50.0f;
        float comb = 0.7f * vs[i * 256 + j] + 0.3f * cs[i * 256 + j];
        float cnt = sc[i * 256 + j];
        float avg = ss[i * 256 + j] / fmaxf(cnt, 1.f);
        e = (cnt > 0.f) ? conf * comb + (1.f - conf) * avg : conf * comb;
    } else {
        float tvi[5], tvj[5]; int tii[5], tij[5];
        #pragma unroll
        for (int k = 0; k < 5; k++) {
            tvi[k] = topv[i * 5 + k]; tii[k] = topi[i * 5 + k];
            tvj[k] = topv[j * 5 + k]; tij[k] = topi[j * 5 + k];
        }
        float trans = 0.f, tot = 0.f;
        #pragma unroll
        for (int k = 0; k < 5; k++) {
            if (!(tvi[k] > 10.f)) continue;
            float vin_i = vs[i * 256 + tii[k]];
            #pragma unroll
            for (int l = 0; l < 5; l++) {
                if (!(tvj[l] > 10.f)) continue;
                int cc = co[tii[k] * 256 + tij[l]];
                if (cc <= 0) continue;
                float w = tvi[k] * tvj[l] / 50.f;
                float sim = vin_i * vs[j * 256 + tij[l]] * vs[tii[k] * 256 + tij[l]];
                trans += w * sim; tot += w;
            }
        }
        e = (tot > 0.f) ? trans / tot : 0.1f * cs[i * 256 + j];
    }
    E[i * 256 + j] = e;
    __shared__ float red[256];
    red[j] = e; __syncthreads();
    for (int off = 128; off > 0; off >>= 1) {
        if (j < off) red[j] = fmaxf(red[j], red[j + off]);
        __syncthreads();
    }
    if (j == 0) partials[i] = red[0];
}

// ---------------- K8: Ep = bf16(I + s*E), s = 1/max (r6-VERIFIED) -----------
// Reinstated: r8's fold-in replicated this conversion 1536x (+27 us). Doing
// it once here costs ~3 us.
__global__ void k_ep(const float* __restrict__ E, const float* __restrict__ partials,
                     unsigned short* __restrict__ Ep) {
    __shared__ float red[256];
    int t = threadIdx.x;
    red[t] = partials[t]; __syncthreads();
    for (int off = 128; off > 0; off >>= 1) {
        if (t < off) red[t] = fmaxf(red[t], red[t + off]);
        __syncthreads();
    }
    float mx = red[0];
    float s = (mx > 0.f) ? 1.0f / mx : 1.0f;
    int base = (blockIdx.x * 256 + t) * 4;
    float4 e4 = *(const float4*)(E + base);
    float ev[4] = {e4.x, e4.y, e4.z, e4.w};
    unsigned short o[4];
    #pragma unroll
    for (int q = 0; q < 4; q++) {
        int g = base + q;
        float v = s * ev[q] + (((g >> 8) == (g & 255)) ? 1.0f : 0.0f);
        o[q] = f2bf(v);
    }
    uint2 w;
    w.x = (unsigned int)o[0] | ((unsigned int)o[1] << 16);
    w.y = (unsigned int)o[2] | ((unsigned int)o[3] << 16);
    *(uint2*)(Ep + base) = w;
}

// ---------------- K9: out[b,:,dtile] = Ep @ x[b,:,dtile] (round-0 VERIFIED) -
// Best-measured einsum of the session (62.9 us vs 76-103 for every variant).
// Ep fully LDS-resident (pitch 264), xT staged per 32-k tile (pitch 40),
// per-tile double-buffered with prefetch. Verbatim from round 0.
#define PEP 264
#define PXT 40
__global__ __launch_bounds__(256, 1) void k_einsum_mfma(
    const unsigned short* __restrict__ Ep, const float* __restrict__ x,
    float* __restrict__ out) {
    extern __shared__ unsigned short smem[];
    unsigned short* eplds = smem;                 // 256*264*2 = 135168 B
    unsigned short* xt    = smem + 256 * PEP;     // 128*40*2  =  10240 B
    int t = threadIdx.x;
    int b = blockIdx.y;
    int d0 = blockIdx.x * 128;

    // ---- stage all of Ep into LDS (row-major, padded pitch) ----
    #pragma unroll
    for (int it = 0; it < 32; it++) {
        int c = it * 256 + t;                     // 16B chunk id (8 bf16)
        uint4 v = *(const uint4*)(Ep + (size_t)c * 8);
        *(uint4*)&eplds[(c >> 5) * PEP + (c & 31) * 8] = v;
    }

    // x staging mapping: thread covers d-col (t&127), k pairs
    int dcol = t & 127;
    int kp = (t >> 7) * 2;                        // 0 or 2
    const float* xb = x + ((size_t)b * 256) * 768 + d0 + dcol;

    int lane = t & 63;
    int lq = lane >> 4, l15 = lane & 15;
    int i0w = (t >> 6) * 64;                      // wave's i-range base

    f32x4 acc[4][8];
    #pragma unroll
    for (int gm = 0; gm < 4; gm++)
        #pragma unroll
        for (int gn = 0; gn < 8; gn++)
            #pragma unroll
            for (int e = 0; e < 4; e++) acc[gm][gn][e] = 0.f;

    float r0[8], r1[8];
    #pragma unroll
    for (int s = 0; s < 8; s++) {                 // prefetch k-tile 0
        int k = kp + 4 * s;
        r0[s] = xb[k * 768];
        r1[s] = xb[(k + 1) * 768];
    }

    for (int kt = 0; kt < 8; kt++) {              // 8 k-tiles of 32
        #pragma unroll
        for (int s = 0; s < 8; s++) {             // cvt+pack -> LDS (transposed)
            int k = kp + 4 * s;
            *(unsigned int*)&xt[dcol * PXT + k] = pack2bf(r0[s], r1[s]);
        }
        __syncthreads();
        if (kt < 7) {                             // prefetch next tile
            const float* xn = xb + (kt + 1) * 32 * 768;
            #pragma unroll
            for (int s = 0; s < 8; s++) {
                int k = kp + 4 * s;
                r0[s] = xn[k * 768];
                r1[s] = xn[(k + 1) * 768];
            }
        }
        int kg = kt * 32 + lq * 8;                // A-frag k offset (global k)
        bf16x8 av[4], bv[8];
        #pragma unroll
        for (int g = 0; g < 4; g++)
            av[g] = *(const bf16x8*)&eplds[(i0w + g * 16 + l15) * PEP + kg];
        #pragma unroll
        for (int g = 0; g < 8; g++)
            bv[g] = *(const bf16x8*)&xt[(g * 16 + l15) * PXT + lq * 8];
        #pragma unroll
        for (int gm = 0; gm < 4; gm++)
            #pragma unroll
            for (int gn = 0; gn < 8; gn++)
                acc[gm][gn] = __builtin_amdgcn_mfma_f32_16x16x32_bf16(
                    av[gm], bv[gn], acc[gm][gn], 0, 0, 0);
        __syncthreads();
    }

    // ---- epilogue: C/D layout col=lane&15, row=(lane>>4)*4+reg ----
    float* ob = out + ((size_t)b * 256) * 768 + d0;
    #pragma unroll
    for (int gm = 0; gm < 4; gm++) {
        #pragma unroll
        for (int gn = 0; gn < 8; gn++) {
            #pragma unroll
            for (int r = 0; r < 4; r++) {
                int i = i0w + gm * 16 + lq * 4 + r;
                int d = gn * 16 + l15;
                ob[(size_t)i * 768 + d] = acc[gm][gn][r];
            }
        }
    }
}

extern "C" void kernel_launch(void* const* d_in, const int* in_sizes, int n_in,
                              void* d_out, int out_size, void* d_ws, size_t ws_size,
                              hipStream_t stream) {
    const float* x   = (const float*)d_in[0];
    const float* cf  = (const float*)d_in[1];
    const float* ctx = (const float*)d_in[2];
    const float* w1  = (const float*)d_in[3];
    const float* b1  = (const float*)d_in[4];
    const float* w2  = (const float*)d_in[5];
    const float* b2  = (const float*)d_in[6];
    const int*   co  = (const int*)d_in[7];
    const int*   ic  = (const int*)d_in[8];
    float* out = (float*)d_out;

    float* ws   = (float*)d_ws;
    float* vsn  = ws;                        // 196608 (unused, layout kept)
    float* csn  = vsn + 196608;              // 196608 (unused)
    float* a    = csn + 196608;              // 98304
    float* vs   = a + 98304;                 // 65536
    float* cs   = vs + 65536;                // 65536
    float* e1   = cs + 65536;                // 65536
    float* ss   = e1 + 65536;                // 65536
    float* sc   = ss + 65536;                // 65536
    float* E    = sc + 65536;                // 65536
    float* topv = E + 65536;                 // 1280
    int*   topi = (int*)(topv + 1280);       // 1280
    float* partials = (float*)(topi + 1280); // 256
    unsigned short* Ep = (unsigned short*)(partials + 256);  // 65536 bf16

    k_stage1<<<288, 256, 0, stream>>>(cf, ctx, w1, a, co, topv, topi, vs, cs);
    k_stage3<<<320, 256, 0, stream>>>(a, b1, w2, b2, vs, cs, ic, e1, co, ss, sc);
    k_assemble<<<256, 256, 0, stream>>>(co, vs, cs, e1, ss, sc, topv, topi, E, partials);
    k_ep<<<64, 256, 0, stream>>>(E, partials, Ep);
    size_t lds_bytes = (size_t)(256 * PEP + 128 * PXT) * sizeof(unsigned short); // 145408
    k_einsum_mfma<<<dim3(6, BATCH), 256, lds_bytes, stream>>>(Ep, x, out);
}

// Round 10
// 252.714 us; speedup vs baseline: 1.1674x; 1.0241x over previous
//
#include <hip/hip_runtime.h>
#include <hip/hip_bf16.h>
#include <math.h>

#define N 256
#define D 768
#define BATCH 128

typedef float f32x4 __attribute__((ext_vector_type(4)));
typedef short bf16x8 __attribute__((ext_vector_type(8)));

// RNE fp32 -> bf16 (no NaN inputs in this problem)
static __device__ __forceinline__ unsigned short f2bf(float f) {
    unsigned int u = __float_as_uint(f);
    u += 0x7fffu + ((u >> 16) & 1u);
    return (unsigned short)(u >> 16);
}
static __device__ __forceinline__ unsigned int pack2bf(float lo, float hi) {
    unsigned int a = __float_as_uint(lo);
    unsigned int b = __float_as_uint(hi);
    a += 0x7fffu + ((a >> 16) & 1u);
    b += 0x7fffu + ((b >> 16) & 1u);
    return (a >> 16) | (b & 0xffff0000u);
}

// ---- Stage 1 (fused): a2 (96) + topk (64) + gram-selfnorm (128)
// r10: LDS pitch 33 -> 34 (even rows -> 8B-aligned float2/b64 reads; staging
// becomes 2-way bank aliasing = free per m136); inner loops use float2 reads
// to halve LDS instruction count (these loops are LDS-issue-bound).
__global__ void k_stage1(const float* __restrict__ cf, const float* __restrict__ ctx,
                         const float* __restrict__ w1, float* __restrict__ a,
                         const int* __restrict__ co, float* __restrict__ topv,
                         int* __restrict__ topi,
                         float* __restrict__ vs, float* __restrict__ cs) {
    __shared__ float sm[2 * 64 * 34];        // a2 Ci+Wj / gram Li+Lj (pitch 34)
    __shared__ float nsum[64][5];
    __shared__ float invn[64];
    int bx = blockIdx.x;
    int t = threadIdx.x;                     // 256
    if (bx < 96) {
        // ---- a = cf @ w1, 32x32 tiles ----
        int bi = bx;
        int i0 = (bi / 12) * 32, j0 = (bi % 12) * 32;
        float (*Ci)[34] = (float(*)[34])sm;
        float (*Wj)[34] = (float(*)[34])(sm + 64 * 34);
        int tx = t & 15, ty = t >> 4;
        float a00 = 0.f, a01 = 0.f, a10 = 0.f, a11 = 0.f;
        for (int k0 = 0; k0 < 768; k0 += 64) {
            #pragma unroll
            for (int s = 0; s < 8; s++) {
                int idx = s * 256 + t;
                int row = idx >> 6, kc = idx & 63;
                Ci[kc][row] = cf[(i0 + row) * 768 + k0 + kc];
                int kr = idx >> 5, col = idx & 31;
                Wj[kr][col] = w1[(k0 + kr) * 384 + j0 + col];
            }
            __syncthreads();
            #pragma unroll 4
            for (int kk = 0; kk < 64; kk++) {
                float2 iv = *(const float2*)&Ci[kk][ty * 2];
                float2 jv = *(const float2*)&Wj[kk][tx * 2];
                a00 += iv.x * jv.x; a01 += iv.x * jv.y;
                a10 += iv.y * jv.x; a11 += iv.y * jv.y;
            }
            __syncthreads();
        }
        a[(i0 + ty * 2)     * 384 + j0 + tx * 2]     = a00;
        a[(i0 + ty * 2)     * 384 + j0 + tx * 2 + 1] = a01;
        a[(i0 + ty * 2 + 1) * 384 + j0 + tx * 2]     = a10;
        a[(i0 + ty * 2 + 1) * 384 + j0 + tx * 2 + 1] = a11;
    } else if (bx < 160) {
        // ---- top-5, one wave per row; named regs (rule #20) ----
        int lane = t & 63;
        int row = (bx - 96) * 4 + (t >> 6);
        int4 v4 = *(const int4*)(co + row * 256 + lane * 4);
        int k0 = v4.x * 256 + (255 - (lane * 4 + 0));
        int k1 = v4.y * 256 + (255 - (lane * 4 + 1));
        int k2 = v4.z * 256 + (255 - (lane * 4 + 2));
        int k3 = v4.w * 256 + (255 - (lane * 4 + 3));
        for (int r = 0; r < 5; r++) {
            int best = max(max(k0, k1), max(k2, k3));
            #pragma unroll
            for (int off = 32; off > 0; off >>= 1) best = max(best, __shfl_xor(best, off, 64));
            int kidx = 255 - (best & 255);
            int val = best >> 8;
            if (lane == 0) { topv[row * 5 + r] = (float)val; topi[row * 5 + r] = kidx; }
            if ((kidx >> 2) == lane) {
                int sel = kidx & 3;
                k0 = (sel == 0) ? -1 : k0;
                k1 = (sel == 1) ? -1 : k1;
                k2 = (sel == 2) ? -1 : k2;
                k3 = (sel == 3) ? -1 : k3;
            }
        }
    } else {
        // ---- gram (vs/cs), 32x32 tiles, self-normalizing ----
        int bx2 = bx - 160;                  // 0..127
        const float* S = (bx2 >= 64) ? ctx : cf;
        float* O       = (bx2 >= 64) ? cs  : vs;
        int bi = bx2 & 63;
        int i0 = (bi >> 3) * 32, j0 = (bi & 7) * 32;
        {
            int r = t >> 2, p = t & 3;
            const float* Srow = S + (size_t)((r < 32) ? (i0 + r) : (j0 + r - 32)) * 768;
            float sq = 0.f;
            for (int j = 0; j < 192; j++) { float v = Srow[p + 4 * j]; sq += v * v; }
            nsum[r][p] = sq;
        }
        __syncthreads();
        if (t < 64) invn[t] = 1.0f / sqrtf(nsum[t][0] + nsum[t][1] + nsum[t][2] + nsum[t][3]);
        __syncthreads();
        float (*Li)[34] = (float(*)[34])sm;
        float (*Lj)[34] = (float(*)[34])(sm + 64 * 34);
        int tx = t & 15, ty = t >> 4;
        float a00 = 0.f, a01 = 0.f, a10 = 0.f, a11 = 0.f;
        for (int k0 = 0; k0 < 768; k0 += 64) {
            #pragma unroll
            for (int s = 0; s < 8; s++) {
                int idx = s * 256 + t;
                int row = idx >> 6, kc = idx & 63;
                Li[kc][row] = S[(i0 + row) * 768 + k0 + kc];
                Lj[kc][row] = S[(j0 + row) * 768 + k0 + kc];
            }
            __syncthreads();
            #pragma unroll 4
            for (int kk = 0; kk < 64; kk++) {
                float2 iv = *(const float2*)&Li[kk][ty * 2];
                float2 jv = *(const float2*)&Lj[kk][tx * 2];
                a00 += iv.x * jv.x; a01 += iv.x * jv.y;
                a10 += iv.y * jv.x; a11 += iv.y * jv.y;
            }
            __syncthreads();
        }
        float ni0 = invn[ty * 2], ni1 = invn[ty * 2 + 1];
        float nj0 = invn[32 + tx * 2], nj1 = invn[32 + tx * 2 + 1];
        O[(i0 + ty * 2)     * 256 + j0 + tx * 2]     = a00 * ni0 * nj0;
        O[(i0 + ty * 2)     * 256 + j0 + tx * 2 + 1] = a01 * ni0 * nj1;
        O[(i0 + ty * 2 + 1) * 256 + j0 + tx * 2]     = a10 * ni1 * nj0;
        O[(i0 + ty * 2 + 1) * 256 + j0 + tx * 2 + 1] = a11 * ni1 * nj1;
    }
}

// ---------------- Stage 3 (fused): e1t (256) + shared2 (64) ----------------
// r10: shared2 pitch 33 -> 34 + float2 LDS reads (8 b32 -> 4 b64 per kk).
__global__ void k_stage3(const float* __restrict__ a, const float* __restrict__ b1,
                         const float* __restrict__ w2, const float* __restrict__ b2,
                         const float* __restrict__ vs, const float* __restrict__ cs,
                         const int* __restrict__ ic, float* __restrict__ e1,
                         const int* __restrict__ co, float* __restrict__ ss,
                         float* __restrict__ sc) {
    __shared__ float sm[12800];
    int bx = blockIdx.x;
    int t = threadIdx.x;
    if (bx < 256) {
        int i0 = (bx >> 4) * 16, j0 = (bx & 15) * 16;
        float (*ai)[388]  = (float(*)[388])sm;
        float (*ajm)[388] = (float(*)[388])(sm + 16 * 388);
        float* sw2 = sm + 2 * 16 * 388;
        for (int idx = t; idx < 16 * 96; idx += 256) {
            int r = idx / 96, c = (idx % 96) * 4;
            *(float4*)&ai[r][c] = *(const float4*)(a + (i0 + r) * 384 + c);
            float4 u  = *(const float4*)(a + (j0 + r) * 384 + c);
            float4 bb = *(const float4*)(b1 + c);
            u.x -= bb.x; u.y -= bb.y; u.z -= bb.z; u.w -= bb.w;
            *(float4*)&ajm[r][c] = u;
        }
        for (int k = t; k < 384; k += 256) sw2[k] = w2[k];
        __syncthreads();
        int tx = t & 15, ty = t >> 4;
        float s = 0.f;
        #pragma unroll 4
        for (int k4 = 0; k4 < 96; k4++) {
            float4 xv = *(const float4*)&ai[ty][k4 * 4];
            float4 yv = *(const float4*)&ajm[tx][k4 * 4];
            float4 wv = *(const float4*)&sw2[k4 * 4];
            s += fmaxf(xv.x - yv.x, 0.f) * wv.x;
            s += fmaxf(xv.y - yv.y, 0.f) * wv.y;
            s += fmaxf(xv.z - yv.z, 0.f) * wv.z;
            s += fmaxf(xv.w - yv.w, 0.f) * wv.w;
        }
        int i = i0 + ty, j = j0 + tx;
        float sig = 1.0f / (1.0f + expf(-(s + b2[0])));
        float comb = 0.7f * vs[i * 256 + j] + 0.3f * cs[i * 256 + j];
        float ci = (float)ic[i], cj = (float)ic[j];
        float mn = fminf(ci, cj), mx = fmaxf(ci, cj);
        float ratio = mn / fmaxf(mx, 1.0f);
        e1[i * 256 + j] = comb * sig * ratio;
    } else {
        int bi = bx - 256;
        int i0 = (bi >> 3) * 32, j0 = (bi & 7) * 32;
        float (*Mi)[34] = (float(*)[34])sm;
        float (*Ai)[34] = (float(*)[34])(sm + 2176);
        float (*Mj)[34] = (float(*)[34])(sm + 4352);
        float (*Aj)[34] = (float(*)[34])(sm + 6528);
        int tx = t & 15, ty = t >> 4;
        float s00=0.f,s01=0.f,s10=0.f,s11=0.f;
        float c00=0.f,c01=0.f,c10=0.f,c11=0.f;
        for (int k0 = 0; k0 < 256; k0 += 64) {
            #pragma unroll
            for (int s = 0; s < 8; s++) {
                int idx = s * 256 + t;
                int row = idx >> 6, kc = idx & 63;
                int civ = co[(i0 + row) * 256 + k0 + kc];
                float aa = civ > 50 ? 1.f : 0.f;
                Ai[kc][row] = aa;
                Mi[kc][row] = aa * vs[(i0 + row) * 256 + k0 + kc];
                int cjv = co[(j0 + row) * 256 + k0 + kc];
                float ab = cjv > 50 ? 1.f : 0.f;
                Aj[kc][row] = ab;
                Mj[kc][row] = ab * vs[(j0 + row) * 256 + k0 + kc];
            }
            __syncthreads();
            #pragma unroll 4
            for (int kk = 0; kk < 64; kk++) {
                float2 mi = *(const float2*)&Mi[kk][ty * 2];
                float2 av = *(const float2*)&Ai[kk][ty * 2];
                float2 mj = *(const float2*)&Mj[kk][tx * 2];
                float2 aj = *(const float2*)&Aj[kk][tx * 2];
                s00 += mi.x*mj.x; s01 += mi.x*mj.y; s10 += mi.y*mj.x; s11 += mi.y*mj.y;
                c00 += av.x*aj.x; c01 += av.x*aj.y; c10 += av.y*aj.x; c11 += av.y*aj.y;
            }
            __syncthreads();
        }
        ss[(i0+ty*2)  *256 + j0+tx*2]   = s00; ss[(i0+ty*2)  *256 + j0+tx*2+1] = s01;
        ss[(i0+ty*2+1)*256 + j0+tx*2]   = s10; ss[(i0+ty*2+1)*256 + j0+tx*2+1] = s11;
        sc[(i0+ty*2)  *256 + j0+tx*2]   = c00; sc[(i0+ty*2)  *256 + j0+tx*2+1] = c01;
        sc[(i0+ty*2+1)*256 + j0+tx*2]   = c10; sc[(i0+ty*2+1)*256 + j0+tx*2+1] = c11;
    }
}

// ---------------- K7: assemble E (tiered), zero diag, per-row max -----------
// r10: tier3 loads made unconditional + mask-multiplied (indices always valid;
// w=0 terms add exact +0.0) -> ~60 independent scattered loads issue together
// instead of a branch-serialized chain. Row-max via wave shuffle (1 barrier).
__global__ void k_assemble(const int* __restrict__ co, const float* __restrict__ vs,
                           const float* __restrict__ cs, const float* __restrict__ e1,
                           const float* __restrict__ ss, const float* __restrict__ sc,
                           const float* __restrict__ topv, const int* __restrict__ topi,
                           float* __restrict__ E, float* __restrict__ partials) {
    int i = blockIdx.x, j = threadIdx.x;
    int cij = co[i * 256 + j];
    float e;
    if (i == j) {
        e = 0.f;
    } else if (cij > 50) {
        e = e1[i * 256 + j];
    } else if (cij > 10) {
        float conf = (float)cij / 50.0f;
        float comb = 0.7f * vs[i * 256 + j] + 0.3f * cs[i * 256 + j];
        float cnt = sc[i * 256 + j];
        float avg = ss[i * 256 + j] / fmaxf(cnt, 1.f);
        e = (cnt > 0.f) ? conf * comb + (1.f - conf) * avg : conf * comb;
    } else {
        float tvi[5], tvj[5]; int tii[5], tij[5];
        #pragma unroll
        for (int k = 0; k < 5; k++) {
            tvi[k] = topv[i * 5 + k]; tii[k] = topi[i * 5 + k];
            tvj[k] = topv[j * 5 + k]; tij[k] = topi[j * 5 + k];
        }
        float vin_i[5], vjn[5];
        #pragma unroll
        for (int k = 0; k < 5; k++) vin_i[k] = vs[i * 256 + tii[k]];
        #pragma unroll
        for (int l = 0; l < 5; l++) vjn[l] = vs[j * 256 + tij[l]];
        float trans = 0.f, tot = 0.f;
        #pragma unroll
        for (int k = 0; k < 5; k++) {
            #pragma unroll
            for (int l = 0; l < 5; l++) {
                int cc = co[tii[k] * 256 + tij[l]];
                float vx = vs[tii[k] * 256 + tij[l]];
                float w = tvi[k] * tvj[l] / 50.f;
                bool m = (tvi[k] > 10.f) & (tvj[l] > 10.f) & (cc > 0);
                w = m ? w : 0.f;
                trans += w * (vin_i[k] * vjn[l] * vx);
                tot += w;
            }
        }
        e = (tot > 0.f) ? trans / tot : 0.1f * cs[i * 256 + j];
    }
    E[i * 256 + j] = e;
    // row max: wave shuffle reduce + tiny LDS combine (1 barrier)
    float m = e;
    #pragma unroll
    for (int off = 32; off > 0; off >>= 1) m = fmaxf(m, __shfl_xor(m, off, 64));
    __shared__ float wred[4];
    if ((j & 63) == 0) wred[j >> 6] = m;
    __syncthreads();
    if (j == 0) partials[i] = fmaxf(fmaxf(wred[0], wred[1]), fmaxf(wred[2], wred[3]));
}

// ---------------- K8: Ep = bf16(I + s*E), s = 1/max (r6-VERIFIED) -----------
__global__ void k_ep(const float* __restrict__ E, const float* __restrict__ partials,
                     unsigned short* __restrict__ Ep) {
    __shared__ float red[256];
    int t = threadIdx.x;
    red[t] = partials[t]; __syncthreads();
    for (int off = 128; off > 0; off >>= 1) {
        if (t < off) red[t] = fmaxf(red[t], red[t + off]);
        __syncthreads();
    }
    float mx = red[0];
    float s = (mx > 0.f) ? 1.0f / mx : 1.0f;
    int base = (blockIdx.x * 256 + t) * 4;
    float4 e4 = *(const float4*)(E + base);
    float ev[4] = {e4.x, e4.y, e4.z, e4.w};
    unsigned short o[4];
    #pragma unroll
    for (int q = 0; q < 4; q++) {
        int g = base + q;
        float v = s * ev[q] + (((g >> 8) == (g & 255)) ? 1.0f : 0.0f);
        o[q] = f2bf(v);
    }
    uint2 w;
    w.x = (unsigned int)o[0] | ((unsigned int)o[1] << 16);
    w.y = (unsigned int)o[2] | ((unsigned int)o[3] << 16);
    *(uint2*)(Ep + base) = w;
}

// ---------------- K9: out[b,:,dtile] = Ep @ x[b,:,dtile] (round-0 VERIFIED) -
// Best-measured einsum of the session (62-64 us). Untouched.
#define PEP 264
#define PXT 40
__global__ __launch_bounds__(256, 1) void k_einsum_mfma(
    const unsigned short* __restrict__ Ep, const float* __restrict__ x,
    float* __restrict__ out) {
    extern __shared__ unsigned short smem[];
    unsigned short* eplds = smem;                 // 256*264*2 = 135168 B
    unsigned short* xt    = smem + 256 * PEP;     // 128*40*2  =  10240 B
    int t = threadIdx.x;
    int b = blockIdx.y;
    int d0 = blockIdx.x * 128;

    #pragma unroll
    for (int it = 0; it < 32; it++) {
        int c = it * 256 + t;
        uint4 v = *(const uint4*)(Ep + (size_t)c * 8);
        *(uint4*)&eplds[(c >> 5) * PEP + (c & 31) * 8] = v;
    }

    int dcol = t & 127;
    int kp = (t >> 7) * 2;
    const float* xb = x + ((size_t)b * 256) * 768 + d0 + dcol;

    int lane = t & 63;
    int lq = lane >> 4, l15 = lane & 15;
    int i0w = (t >> 6) * 64;

    f32x4 acc[4][8];
    #pragma unroll
    for (int gm = 0; gm < 4; gm++)
        #pragma unroll
        for (int gn = 0; gn < 8; gn++)
            #pragma unroll
            for (int e = 0; e < 4; e++) acc[gm][gn][e] = 0.f;

    float r0[8], r1[8];
    #pragma unroll
    for (int s = 0; s < 8; s++) {
        int k = kp + 4 * s;
        r0[s] = xb[k * 768];
        r1[s] = xb[(k + 1) * 768];
    }

    for (int kt = 0; kt < 8; kt++) {
        #pragma unroll
        for (int s = 0; s < 8; s++) {
            int k = kp + 4 * s;
            *(unsigned int*)&xt[dcol * PXT + k] = pack2bf(r0[s], r1[s]);
        }
        __syncthreads();
        if (kt < 7) {
            const float* xn = xb + (kt + 1) * 32 * 768;
            #pragma unroll
            for (int s = 0; s < 8; s++) {
                int k = kp + 4 * s;
                r0[s] = xn[k * 768];
                r1[s] = xn[(k + 1) * 768];
            }
        }
        int kg = kt * 32 + lq * 8;
        bf16x8 av[4], bv[8];
        #pragma unroll
        for (int g = 0; g < 4; g++)
            av[g] = *(const bf16x8*)&eplds[(i0w + g * 16 + l15) * PEP + kg];
        #pragma unroll
        for (int g = 0; g < 8; g++)
            bv[g] = *(const bf16x8*)&xt[(g * 16 + l15) * PXT + lq * 8];
        #pragma unroll
        for (int gm = 0; gm < 4; gm++)
            #pragma unroll
            for (int gn = 0; gn < 8; gn++)
                acc[gm][gn] = __builtin_amdgcn_mfma_f32_16x16x32_bf16(
                    av[gm], bv[gn], acc[gm][gn], 0, 0, 0);
        __syncthreads();
    }

    float* ob = out + ((size_t)b * 256) * 768 + d0;
    #pragma unroll
    for (int gm = 0; gm < 4; gm++) {
        #pragma unroll
        for (int gn = 0; gn < 8; gn++) {
            #pragma unroll
            for (int r = 0; r < 4; r++) {
                int i = i0w + gm * 16 + lq * 4 + r;
                int d = gn * 16 + l15;
                ob[(size_t)i * 768 + d] = acc[gm][gn][r];
            }
        }
    }
}

extern "C" void kernel_launch(void* const* d_in, const int* in_sizes, int n_in,
                              void* d_out, int out_size, void* d_ws, size_t ws_size,
                              hipStream_t stream) {
    const float* x   = (const float*)d_in[0];
    const float* cf  = (const float*)d_in[1];
    const float* ctx = (const float*)d_in[2];
    const float* w1  = (const float*)d_in[3];
    const float* b1  = (const float*)d_in[4];
    const float* w2  = (const float*)d_in[5];
    const float* b2  = (const float*)d_in[6];
    const int*   co  = (const int*)d_in[7];
    const int*   ic  = (const int*)d_in[8];
    float* out = (float*)d_out;

    float* ws   = (float*)d_ws;
    float* vsn  = ws;                        // 196608 (unused, layout kept)
    float* csn  = vsn + 196608;              // 196608 (unused)
    float* a    = csn + 196608;              // 98304
    float* vs   = a + 98304;                 // 65536
    float* cs   = vs + 65536;                // 65536
    float* e1   = cs + 65536;                // 65536
    float* ss   = e1 + 65536;                // 65536
    float* sc   = ss + 65536;                // 65536
    float* E    = sc + 65536;                // 65536
    float* topv = E + 65536;                 // 1280
    int*   topi = (int*)(topv + 1280);       // 1280
    float* partials = (float*)(topi + 1280); // 256
    unsigned short* Ep = (unsigned short*)(partials + 256);  // 65536 bf16

    k_stage1<<<288, 256, 0, stream>>>(cf, ctx, w1, a, co, topv, topi, vs, cs);
    k_stage3<<<320, 256, 0, stream>>>(a, b1, w2, b2, vs, cs, ic, e1, co, ss, sc);
    k_assemble<<<256, 256, 0, stream>>>(co, vs, cs, e1, ss, sc, topv, topi, E, partials);
    k_ep<<<64, 256, 0, stream>>>(E, partials, Ep);
    size_t lds_bytes = (size_t)(256 * PEP + 128 * PXT) * sizeof(unsigned short); // 145408
    k_einsum_mfma<<<dim3(6, BATCH), 256, lds_bytes, stream>>>(Ep, x, out);
}